// Round 1
// baseline (743.210 us; speedup 1.0000x reference)
//
#include <hip/hip_runtime.h>
#include <math.h>

#define NCLS 10
#define KNN 3

__device__ __forceinline__ float digammaf_dev(float x) {
    // psi(x) via recurrence up to x>=6, then asymptotic series. x >= 1 assumed.
    float r = 0.0f;
    while (x < 6.0f) { r -= 1.0f / x; x += 1.0f; }
    float inv = 1.0f / x;
    float inv2 = inv * inv;
    float s = logf(x) - 0.5f * inv
            - inv2 * (0.083333333333f - inv2 * (0.0083333333333f - inv2 * 0.0039682539683f));
    return r + s;
}

__global__ void zero_kernel(int* cls) {
    if (threadIdx.x < 16) cls[threadIdx.x] = 0;
}

// sq[i] = |x_i|^2 (wave per row), plus class bincount
__global__ void prep_kernel(const float* __restrict__ X, const int* __restrict__ y,
                            float* __restrict__ sq, int* __restrict__ cls, int N) {
    int wave = threadIdx.x >> 6;
    int lane = threadIdx.x & 63;
    int row = blockIdx.x * 4 + wave;
    if (row >= N) return;
    float2 v = *(const float2*)(X + (size_t)row * 128 + lane * 2);
    float s = fmaf(v.x, v.x, v.y * v.y);
    #pragma unroll
    for (int off = 32; off > 0; off >>= 1) s += __shfl_down(s, off);
    if (lane == 0) {
        sq[row] = s;
        atomicAdd(&cls[y[row]], 1);
    }
}

// PASS 1: per-row top-4 smallest same-class d2 over this block's j-chunk.
// PASS 2: per-row count of d2 <= anchor over this block's j-chunk.
// d2 computation is IDENTICAL (same fmaf chain) in both instantiations so the
// anchor value compares bit-exactly in pass 2.
template <int PASS>
__global__ __launch_bounds__(256, 2)
void pass_kernel(const float* __restrict__ X, const int* __restrict__ y,
                 const float* __restrict__ sq, const float* __restrict__ anchor,
                 float* __restrict__ top4p, int* __restrict__ cntp, int N, int NCH) {
    constexpr int D = 128, TI = 64, TJ = 64, SD = 132;  // SD=132: 16B-aligned rows, 2-way-free banks
    __shared__ __align__(16) float smem[(TI + TJ) * SD];
    float* Xi = smem;
    float* Xj = smem + TI * SD;

    const int t = threadIdx.x;
    const int ibase = blockIdx.x * TI;
    const int ch = blockIdx.y;
    const int CHUNK = N / NCH;
    const int jbase0 = ch * CHUNK;

    // stage Xi (64 rows x 128)
    {
        int lrow = t >> 2, q = t & 3;
        const float* src = X + (size_t)(ibase + lrow) * D + q * 32;
        float* dst = Xi + lrow * SD + q * 32;
        #pragma unroll
        for (int k = 0; k < 8; ++k)
            *(float4*)(dst + 4 * k) = *(const float4*)(src + 4 * k);
    }

    const int tx = t & 15;   // i-group: rows tx + 16*m  (stride-16 interleave keeps LDS 2-way)
    const int ty = t >> 4;   // j-group: cols 4*ty + n

    float sqi[4]; int yi[4];
    #pragma unroll
    for (int m = 0; m < 4; ++m) {
        int i = ibase + tx + 16 * m;
        sqi[m] = sq[i];
        yi[m] = y[i];
    }

    float tp[4][4];
    int cnt[4];
    float anc[4];
    if (PASS == 1) {
        #pragma unroll
        for (int m = 0; m < 4; ++m)
            #pragma unroll
            for (int s = 0; s < 4; ++s) tp[m][s] = 1e30f;
    } else {
        #pragma unroll
        for (int m = 0; m < 4; ++m) {
            cnt[m] = 0;
            anc[m] = anchor[ibase + tx + 16 * m];
        }
    }

    for (int jt = 0; jt < CHUNK / TJ; ++jt) {
        const int jbase = jbase0 + jt * TJ;
        __syncthreads();  // previous tile fully consumed
        {
            int lrow = t >> 2, q = t & 3;
            const float* src = X + (size_t)(jbase + lrow) * D + q * 32;
            float* dst = Xj + lrow * SD + q * 32;
            #pragma unroll
            for (int k = 0; k < 8; ++k)
                *(float4*)(dst + 4 * k) = *(const float4*)(src + 4 * k);
        }
        __syncthreads();

        float sqj[4]; int yj[4];
        #pragma unroll
        for (int n = 0; n < 4; ++n) {
            int j = jbase + 4 * ty + n;
            sqj[n] = sq[j];
            yj[n] = y[j];
        }

        float acc[4][4];
        #pragma unroll
        for (int m = 0; m < 4; ++m)
            #pragma unroll
            for (int n = 0; n < 4; ++n) acc[m][n] = 0.0f;

        #pragma unroll 8
        for (int d = 0; d < D; d += 4) {
            float4 a[4], b[4];
            #pragma unroll
            for (int m = 0; m < 4; ++m) a[m] = *(const float4*)(Xi + (tx + 16 * m) * SD + d);
            #pragma unroll
            for (int n = 0; n < 4; ++n) b[n] = *(const float4*)(Xj + (4 * ty + n) * SD + d);
            #pragma unroll
            for (int m = 0; m < 4; ++m)
                #pragma unroll
                for (int n = 0; n < 4; ++n) {
                    float v = acc[m][n];
                    v = fmaf(a[m].x, b[n].x, v);
                    v = fmaf(a[m].y, b[n].y, v);
                    v = fmaf(a[m].z, b[n].z, v);
                    v = fmaf(a[m].w, b[n].w, v);
                    acc[m][n] = v;
                }
        }

        #pragma unroll
        for (int m = 0; m < 4; ++m)
            #pragma unroll
            for (int n = 0; n < 4; ++n) {
                float d2 = fmaf(-2.0f, acc[m][n], sqi[m] + sqj[n]);
                d2 = fmaxf(d2, 0.0f);
                if (PASS == 1) {
                    float v = (yi[m] == yj[n]) ? d2 : 1e30f;
                    if (v < tp[m][3]) {
                        tp[m][3] = v;
                        if (tp[m][3] < tp[m][2]) { float w = tp[m][2]; tp[m][2] = tp[m][3]; tp[m][3] = w; }
                        if (tp[m][2] < tp[m][1]) { float w = tp[m][1]; tp[m][1] = tp[m][2]; tp[m][2] = w; }
                        if (tp[m][1] < tp[m][0]) { float w = tp[m][0]; tp[m][0] = tp[m][1]; tp[m][1] = w; }
                    }
                } else {
                    cnt[m] += (d2 <= anc[m]) ? 1 : 0;
                }
            }
    }

    __syncthreads();  // done reading Xj; reuse it as merge scratch
    if (PASS == 1) {
        #pragma unroll
        for (int m = 0; m < 4; ++m)
            #pragma unroll
            for (int s = 0; s < 4; ++s)
                Xj[(tx + 16 * m) * 64 + ty * 4 + s] = tp[m][s];
        __syncthreads();
        if (t < TI) {
            float best[4] = {1e30f, 1e30f, 1e30f, 1e30f};
            for (int c = 0; c < 64; ++c) {
                float v = Xj[t * 64 + c];
                if (v < best[3]) {
                    best[3] = v;
                    if (best[3] < best[2]) { float w = best[2]; best[2] = best[3]; best[3] = w; }
                    if (best[2] < best[1]) { float w = best[1]; best[1] = best[2]; best[2] = w; }
                    if (best[1] < best[0]) { float w = best[0]; best[0] = best[1]; best[1] = w; }
                }
            }
            #pragma unroll
            for (int s = 0; s < 4; ++s)
                top4p[((size_t)(ibase + t) * NCH + ch) * 4 + s] = best[s];
        }
    } else {
        int* icnt = (int*)Xj;
        #pragma unroll
        for (int m = 0; m < 4; ++m) icnt[(tx + 16 * m) * 16 + ty] = cnt[m];
        __syncthreads();
        if (t < TI) {
            int s = 0;
            for (int c = 0; c < 16; ++c) s += icnt[t * 16 + c];
            cntp[(size_t)(ibase + t) * NCH + ch] = s;
        }
    }
}

// merge the 8 per-chunk top-4 lists -> anchor d2 (4th smallest overall, self included)
__global__ void anchor_kernel(const float* __restrict__ top4p, float* __restrict__ anchor,
                              int N, int NCH) {
    int row = blockIdx.x * blockDim.x + threadIdx.x;
    if (row >= N) return;
    float best[4] = {1e30f, 1e30f, 1e30f, 1e30f};
    for (int c = 0; c < NCH * 4; ++c) {
        float v = top4p[(size_t)row * NCH * 4 + c];
        if (v < best[3]) {
            best[3] = v;
            if (best[3] < best[2]) { float w = best[2]; best[2] = best[3]; best[3] = w; }
            if (best[2] < best[1]) { float w = best[1]; best[1] = best[2]; best[2] = w; }
            if (best[1] < best[0]) { float w = best[0]; best[0] = best[1]; best[1] = w; }
        }
    }
    anchor[row] = best[3];
}

__global__ void finalize_kernel(const int* __restrict__ cntp, const int* __restrict__ cls,
                                float* __restrict__ out, int N, int NCH) {
    __shared__ float red[256];
    int t = threadIdx.x;
    float ls = 0.0f;
    for (int row = t; row < N; row += 256) {
        int m = 0;
        for (int c = 0; c < NCH; ++c) m += cntp[(size_t)row * NCH + c];
        m -= 1;  // exclude self
        ls += digammaf_dev((float)m);
    }
    red[t] = ls;
    __syncthreads();
    for (int s = 128; s > 0; s >>= 1) {
        if (t < s) red[t] += red[t + s];
        __syncthreads();
    }
    if (t == 0) {
        float Nf = (float)N;
        float avg_m = red[0] / Nf;
        float avgNx = 0.0f;
        for (int c = 0; c < NCLS; ++c) {
            float nx = (float)cls[c];
            if (nx > 0.0f) avgNx += (nx / Nf) * digammaf_dev(nx);
        }
        float mi = digammaf_dev(Nf) - avgNx + digammaf_dev((float)KNN) - avg_m;
        out[0] = fmaxf(mi / logf(2.0f), 0.0f);
    }
}

extern "C" void kernel_launch(void* const* d_in, const int* in_sizes, int n_in,
                              void* d_out, int out_size, void* d_ws, size_t ws_size,
                              hipStream_t stream) {
    const float* X = (const float*)d_in[0];
    const int* y = (const int*)d_in[1];
    float* out = (float*)d_out;
    const int N = in_sizes[1];        // 8192
    const int NCH = 8;                // j-chunks

    // workspace layout
    float* sq      = (float*)d_ws;                       // N
    float* anchors = sq + N;                             // N
    float* top4p   = anchors + N;                        // N * NCH * 4
    int*   cntp    = (int*)(top4p + (size_t)N * NCH * 4);// N * NCH
    int*   cls     = cntp + (size_t)N * NCH;             // 16

    zero_kernel<<<1, 64, 0, stream>>>(cls);
    prep_kernel<<<N / 4, 256, 0, stream>>>(X, y, sq, cls, N);
    pass_kernel<1><<<dim3(N / 64, NCH), 256, 0, stream>>>(X, y, sq, anchors, top4p, cntp, N, NCH);
    anchor_kernel<<<(N + 255) / 256, 256, 0, stream>>>(top4p, anchors, N, NCH);
    pass_kernel<2><<<dim3(N / 64, NCH), 256, 0, stream>>>(X, y, sq, anchors, top4p, cntp, N, NCH);
    finalize_kernel<<<1, 256, 0, stream>>>(cntp, cls, out, N, NCH);
}

// Round 2
// 359.852 us; speedup vs baseline: 2.0653x; 2.0653x over previous
//
#include <hip/hip_runtime.h>
#include <hip/hip_bf16.h>
#include <math.h>

#define NCLS 10
#define NTOT 8192
#define BM 128
#define BN 128
#define BK 64
#define NJT 2
#define NJG (NTOT / (BN * NJT))   // 32
#define ITILES (NTOT / BM)        // 64

using short8 = __attribute__((ext_vector_type(8))) short;
using f32x4  = __attribute__((ext_vector_type(4))) float;

__device__ __forceinline__ float digammaf_dev(float x) {
    float r = 0.0f;
    while (x < 6.0f) { r -= 1.0f / x; x += 1.0f; }
    float inv = 1.0f / x;
    float inv2 = inv * inv;
    float s = logf(x) - 0.5f * inv
            - inv2 * (0.083333333333f - inv2 * (0.0083333333333f - inv2 * 0.0039682539683f));
    return r + s;
}

__device__ __forceinline__ void ins4(float v, float& b0, float& b1, float& b2, float& b3) {
    if (v < b3) {
        b3 = v;
        if (b3 < b2) { float w = b2; b2 = b3; b3 = w; }
        if (b2 < b1) { float w = b1; b1 = b2; b2 = w; }
        if (b1 < b0) { float w = b0; b0 = b1; b1 = w; }
    }
}

__device__ __forceinline__ void gload_lds16(const void* g, void* s) {
    __builtin_amdgcn_global_load_lds((const __attribute__((address_space(1))) void*)g,
                                     (__attribute__((address_space(3))) void*)s, 16, 0, 0);
}

__global__ void zero_kernel(int* cls) {
    if (threadIdx.x < 16) cls[threadIdx.x] = 0;
}

// per row: sq (fp32), class bincount, and XS[row][0..127]=hi(bf16), [128..255]=lo(bf16)
__global__ void prep_kernel(const float* __restrict__ X, const int* __restrict__ y,
                            float* __restrict__ sq, unsigned short* __restrict__ XS,
                            int* __restrict__ cls) {
    int wave = threadIdx.x >> 6, lane = threadIdx.x & 63;
    int row = blockIdx.x * 4 + wave;
    float2 v = *(const float2*)(X + (size_t)row * 128 + lane * 2);
    __hip_bfloat16 h0 = __float2bfloat16(v.x);
    __hip_bfloat16 h1 = __float2bfloat16(v.y);
    float hf0 = __bfloat162float(h0), hf1 = __bfloat162float(h1);
    __hip_bfloat16 l0 = __float2bfloat16(v.x - hf0);
    __hip_bfloat16 l1 = __float2bfloat16(v.y - hf1);
    ushort2 hp, lp;
    hp.x = *(unsigned short*)&h0; hp.y = *(unsigned short*)&h1;
    lp.x = *(unsigned short*)&l0; lp.y = *(unsigned short*)&l1;
    *(ushort2*)(XS + (size_t)row * 256 + lane * 2) = hp;
    *(ushort2*)(XS + (size_t)row * 256 + 128 + lane * 2) = lp;
    float s = fmaf(v.x, v.x, v.y * v.y);
    #pragma unroll
    for (int off = 32; off > 0; off >>= 1) s += __shfl_down(s, off);
    if (lane == 0) {
        sq[row] = s;
        atomicAdd(&cls[y[row]], 1);
    }
}

// MFMA distance pass. dot = sum_{k<384} A[i][k]*B[j][k] with A=[hi|hi|lo], B=[hi|lo|hi]
// both sourced from XS=[hi|lo] via per-BK offset remap. d2 = sqi + sqj - 2*dot.
// PASS 1: per-row top-4 smallest same-class d2 over this block's 256-col span.
// PASS 2: per-row count of d2 <= anchor.
template <int PASS>
__global__ __launch_bounds__(256, 2)
void pass_kernel(const unsigned short* __restrict__ XS, const int* __restrict__ y,
                 const float* __restrict__ sq, const float* __restrict__ anchor,
                 float* __restrict__ top4p, int* __restrict__ cntp) {
    __shared__ __align__(16) char smem[40960];
    unsigned short* As = (unsigned short*)smem;            // [128][64] bf16
    unsigned short* Bs = (unsigned short*)(smem + 16384);  // [128][64] bf16

    const int t = threadIdx.x;
    const int w = t >> 6, l = t & 63;
    const int wr = w >> 1, wc = w & 1;
    const int lg = l >> 4, lo16 = l & 15;

    // XCD-aware bijective swizzle (2048 % 8 == 0)
    int bid = blockIdx.x;
    int wg = (bid & 7) * ((ITILES * NJG) >> 3) + (bid >> 3);
    const int it = wg & (ITILES - 1), jg = wg / ITILES;
    const int ibase = it * BM;

    float sqi[16]; int yi[16]; float anc[16];
    #pragma unroll
    for (int mi = 0; mi < 4; ++mi)
        #pragma unroll
        for (int r = 0; r < 4; ++r) {
            int row = ibase + wr * 64 + mi * 16 + lg * 4 + r;
            sqi[mi * 4 + r] = sq[row];
            if (PASS == 1) yi[mi * 4 + r] = y[row];
            else anc[mi * 4 + r] = anchor[row];
        }

    float r00 = 1e30f, r01 = 1e30f, r02 = 1e30f, r03 = 1e30f;  // running top4, row ibase+t   (t<64)
    float r10 = 1e30f, r11 = 1e30f, r12 = 1e30f, r13 = 1e30f;  // running top4, row ibase+64+t
    int runc = 0;                                              // running count, row ibase+t (t<128)

    #pragma unroll 1
    for (int jt = 0; jt < NJT; ++jt) {
        const int jbase = jg * (BN * NJT) + jt * BN;
        float sqj[4]; int yj[4];
        #pragma unroll
        for (int ni = 0; ni < 4; ++ni) {
            int col = jbase + wc * 64 + ni * 16 + lo16;
            sqj[ni] = sq[col];
            if (PASS == 1) yj[ni] = y[col];
        }
        f32x4 acc[4][4];
        f32x4 zz = {0.0f, 0.0f, 0.0f, 0.0f};
        #pragma unroll
        for (int mi = 0; mi < 4; ++mi)
            #pragma unroll
            for (int ni = 0; ni < 4; ++ni) acc[mi][ni] = zz;

        #pragma unroll 1
        for (int ks = 0; ks < 6; ++ks) {
            // K remap: A concat [hi|hi|lo], B concat [hi|lo|hi] from XS=[hi(128)|lo(128)]
            const int kA = (ks >= 4) ? (ks - 2) * 64 : (ks & 1) * 64;
            const int kB = ((ks >= 4) ? (ks - 4) : ks) * 64;
            __syncthreads();
            {
                const int srow = w * 32 + (l >> 3);
                const int scol = (l & 7) * 8;
                const unsigned short* gA = XS + (size_t)(ibase + srow) * 256 + kA + scol;
                const unsigned short* gB = XS + (size_t)(jbase + srow) * 256 + kB + scol;
                #pragma unroll
                for (int q = 0; q < 4; ++q)
                    gload_lds16(gA + (size_t)q * 8 * 256, As + w * 2048 + q * 512);
                #pragma unroll
                for (int q = 0; q < 4; ++q)
                    gload_lds16(gB + (size_t)q * 8 * 256, Bs + w * 2048 + q * 512);
            }
            __syncthreads();
            #pragma unroll
            for (int kk = 0; kk < 2; ++kk) {
                short8 aF[4], bF[4];
                #pragma unroll
                for (int mi = 0; mi < 4; ++mi)
                    aF[mi] = *(const short8*)(As + (wr * 64 + mi * 16 + lo16) * 64 + kk * 32 + lg * 8);
                #pragma unroll
                for (int ni = 0; ni < 4; ++ni)
                    bF[ni] = *(const short8*)(Bs + (wc * 64 + ni * 16 + lo16) * 64 + kk * 32 + lg * 8);
                #pragma unroll
                for (int mi = 0; mi < 4; ++mi)
                    #pragma unroll
                    for (int ni = 0; ni < 4; ++ni)
                        acc[mi][ni] = __builtin_amdgcn_mfma_f32_16x16x32_bf16(
                            aF[mi], bF[ni], acc[mi][ni], 0, 0, 0);
            }
        }

        if (PASS == 1) {
            float* scanbuf = (float*)smem;             // [64][132]
            float* partial = (float*)(smem + 33792);   // [64][17]
            #pragma unroll
            for (int h = 0; h < 2; ++h) {
                __syncthreads();
                if (wr == h) {
                    #pragma unroll
                    for (int mi = 0; mi < 4; ++mi)
                        #pragma unroll
                        for (int r = 0; r < 4; ++r) {
                            int rl = mi * 16 + lg * 4 + r;
                            #pragma unroll
                            for (int ni = 0; ni < 4; ++ni) {
                                float d2 = fmaf(-2.0f, acc[mi][ni][r], sqi[mi * 4 + r] + sqj[ni]);
                                d2 = fmaxf(d2, 0.0f);
                                float v = (yi[mi * 4 + r] == yj[ni]) ? d2 : 1e30f;
                                scanbuf[rl * 132 + wc * 64 + ni * 16 + lo16] = v;
                            }
                        }
                }
                __syncthreads();
                {
                    int row = t >> 2, seg = t & 3;
                    float b0 = 1e30f, b1 = 1e30f, b2 = 1e30f, b3 = 1e30f;
                    #pragma unroll 8
                    for (int i = 0; i < 32; ++i) {
                        float v = scanbuf[row * 132 + seg + 4 * i];
                        ins4(v, b0, b1, b2, b3);
                    }
                    partial[row * 17 + seg * 4 + 0] = b0;
                    partial[row * 17 + seg * 4 + 1] = b1;
                    partial[row * 17 + seg * 4 + 2] = b2;
                    partial[row * 17 + seg * 4 + 3] = b3;
                }
                __syncthreads();
                if (t < 64) {
                    if (h == 0) {
                        for (int c = 0; c < 16; ++c) {
                            float v = partial[t * 17 + c];
                            ins4(v, r00, r01, r02, r03);
                        }
                    } else {
                        for (int c = 0; c < 16; ++c) {
                            float v = partial[t * 17 + c];
                            ins4(v, r10, r11, r12, r13);
                        }
                    }
                }
            }
        } else {
            int* cbuf = (int*)smem;  // [128][33]
            __syncthreads();
            #pragma unroll
            for (int mi = 0; mi < 4; ++mi)
                #pragma unroll
                for (int r = 0; r < 4; ++r) {
                    int p = 0;
                    #pragma unroll
                    for (int ni = 0; ni < 4; ++ni) {
                        float d2 = fmaf(-2.0f, acc[mi][ni][r], sqi[mi * 4 + r] + sqj[ni]);
                        d2 = fmaxf(d2, 0.0f);
                        p += (d2 <= anc[mi * 4 + r]) ? 1 : 0;
                    }
                    cbuf[(wr * 64 + mi * 16 + lg * 4 + r) * 33 + wc * 16 + lo16] = p;
                }
            __syncthreads();
            if (t < 128) {
                int s = 0;
                #pragma unroll 8
                for (int c = 0; c < 32; ++c) s += cbuf[t * 33 + c];
                runc += s;
            }
        }
    }

    if (PASS == 1) {
        if (t < 64) {
            size_t b0 = ((size_t)(ibase + t) * NJG + jg) * 4;
            top4p[b0 + 0] = r00; top4p[b0 + 1] = r01; top4p[b0 + 2] = r02; top4p[b0 + 3] = r03;
            size_t b1i = ((size_t)(ibase + 64 + t) * NJG + jg) * 4;
            top4p[b1i + 0] = r10; top4p[b1i + 1] = r11; top4p[b1i + 2] = r12; top4p[b1i + 3] = r13;
        }
    } else {
        if (t < 128) cntp[(size_t)(ibase + t) * NJG + jg] = runc;
    }
}

__global__ void anchor_kernel(const float* __restrict__ top4p, float* __restrict__ anchor) {
    int row = blockIdx.x * 256 + threadIdx.x;
    if (row >= NTOT) return;
    float b0 = 1e30f, b1 = 1e30f, b2 = 1e30f, b3 = 1e30f;
    const float* p = top4p + (size_t)row * NJG * 4;
    for (int c = 0; c < NJG * 4; ++c) ins4(p[c], b0, b1, b2, b3);
    anchor[row] = b3;
}

// sum count partials -> m_i -> digamma -> per-block partial sum (deterministic tree)
__global__ void reduce_kernel(const int* __restrict__ cntp, float* __restrict__ partials) {
    __shared__ float red[256];
    int t = threadIdx.x;
    int row = blockIdx.x * 256 + t;
    int s = 0;
    for (int c = 0; c < NJG; ++c) s += cntp[(size_t)row * NJG + c];
    red[t] = digammaf_dev((float)(s - 1));
    __syncthreads();
    for (int h = 128; h > 0; h >>= 1) {
        if (t < h) red[t] += red[t + h];
        __syncthreads();
    }
    if (t == 0) partials[blockIdx.x] = red[0];
}

__global__ void finalize_kernel(const float* __restrict__ partials, const int* __restrict__ cls,
                                float* __restrict__ out) {
    if (threadIdx.x == 0) {
        float acc = 0.0f;
        for (int c = 0; c < NTOT / 256; ++c) acc += partials[c];
        float Nf = (float)NTOT;
        float avg_m = acc / Nf;
        float avgNx = 0.0f;
        for (int c = 0; c < NCLS; ++c) {
            float nx = (float)cls[c];
            if (nx > 0.0f) avgNx += (nx / Nf) * digammaf_dev(nx);
        }
        float mi = digammaf_dev(Nf) - avgNx + digammaf_dev(3.0f) - avg_m;
        out[0] = fmaxf(mi / logf(2.0f), 0.0f);
    }
}

extern "C" void kernel_launch(void* const* d_in, const int* in_sizes, int n_in,
                              void* d_out, int out_size, void* d_ws, size_t ws_size,
                              hipStream_t stream) {
    const float* X = (const float*)d_in[0];
    const int* y = (const int*)d_in[1];
    float* out = (float*)d_out;

    // workspace layout (bytes): sq | anchors | partials | cls | XS | top4p | cntp
    float* sq       = (float*)d_ws;                                   // 8192
    float* anchors  = sq + NTOT;                                      // 8192
    float* partials = anchors + NTOT;                                 // 64
    int*   cls      = (int*)(partials + 64);                          // 16
    unsigned short* XS = (unsigned short*)(cls + 16);                 // 8192*256
    float* top4p    = (float*)(XS + (size_t)NTOT * 256);              // 8192*32*4
    int*   cntp     = (int*)(top4p + (size_t)NTOT * NJG * 4);         // 8192*32

    zero_kernel<<<1, 64, 0, stream>>>(cls);
    prep_kernel<<<NTOT / 4, 256, 0, stream>>>(X, y, sq, XS, cls);
    pass_kernel<1><<<ITILES * NJG, 256, 0, stream>>>(XS, y, sq, anchors, top4p, cntp);
    anchor_kernel<<<NTOT / 256, 256, 0, stream>>>(top4p, anchors);
    pass_kernel<2><<<ITILES * NJG, 256, 0, stream>>>(XS, y, sq, anchors, top4p, cntp);
    reduce_kernel<<<NTOT / 256, 256, 0, stream>>>(cntp, partials);
    finalize_kernel<<<1, 64, 0, stream>>>(partials, cls, out);
}

// Round 3
// 320.214 us; speedup vs baseline: 2.3210x; 1.1238x over previous
//
#include <hip/hip_runtime.h>
#include <hip/hip_bf16.h>
#include <math.h>

#define NCLS 10
#define NTOT 8192
#define BM 128
#define BN 128
#define NJT 2
#define NJG (NTOT / (BN * NJT))   // 32
#define ITILES (NTOT / BM)        // 64
#define NSTEP (6 * NJT)           // 12

using short8 = __attribute__((ext_vector_type(8))) short;
using f32x4  = __attribute__((ext_vector_type(4))) float;

__device__ __forceinline__ float digammaf_dev(float x) {
    float r = 0.0f;
    while (x < 6.0f) { r -= 1.0f / x; x += 1.0f; }
    float inv = 1.0f / x;
    float inv2 = inv * inv;
    float s = logf(x) - 0.5f * inv
            - inv2 * (0.083333333333f - inv2 * (0.0083333333333f - inv2 * 0.0039682539683f));
    return r + s;
}

__device__ __forceinline__ void ins4(float v, float& b0, float& b1, float& b2, float& b3) {
    if (v < b3) {
        b3 = v;
        if (b3 < b2) { float w = b2; b2 = b3; b3 = w; }
        if (b2 < b1) { float w = b1; b1 = b2; b2 = w; }
        if (b1 < b0) { float w = b0; b0 = b1; b1 = w; }
    }
}

__device__ __forceinline__ void cmpswap(float& a, float& b) {
    float lo = fminf(a, b), hi = fmaxf(a, b);
    a = lo; b = hi;
}

__device__ __forceinline__ void gload_lds16(const void* g, void* s) {
    __builtin_amdgcn_global_load_lds((const __attribute__((address_space(1))) void*)g,
                                     (__attribute__((address_space(3))) void*)s, 16, 0, 0);
}

__global__ void zero_kernel(int* cls) {
    if (threadIdx.x < 16) cls[threadIdx.x] = 0;
}

// per row: sq (fp32), class bincount, and XS[row][0..127]=hi(bf16), [128..255]=lo(bf16)
__global__ void prep_kernel(const float* __restrict__ X, const int* __restrict__ y,
                            float* __restrict__ sq, unsigned short* __restrict__ XS,
                            int* __restrict__ cls) {
    int wave = threadIdx.x >> 6, lane = threadIdx.x & 63;
    int row = blockIdx.x * 4 + wave;
    float2 v = *(const float2*)(X + (size_t)row * 128 + lane * 2);
    __hip_bfloat16 h0 = __float2bfloat16(v.x);
    __hip_bfloat16 h1 = __float2bfloat16(v.y);
    float hf0 = __bfloat162float(h0), hf1 = __bfloat162float(h1);
    __hip_bfloat16 l0 = __float2bfloat16(v.x - hf0);
    __hip_bfloat16 l1 = __float2bfloat16(v.y - hf1);
    ushort2 hp, lp;
    hp.x = *(unsigned short*)&h0; hp.y = *(unsigned short*)&h1;
    lp.x = *(unsigned short*)&l0; lp.y = *(unsigned short*)&l1;
    *(ushort2*)(XS + (size_t)row * 256 + lane * 2) = hp;
    *(ushort2*)(XS + (size_t)row * 256 + 128 + lane * 2) = lp;
    float s = fmaf(v.x, v.x, v.y * v.y);
    #pragma unroll
    for (int off = 32; off > 0; off >>= 1) s += __shfl_down(s, off);
    if (lane == 0) {
        sq[row] = s;
        atomicAdd(&cls[y[row]], 1);
    }
}

// MFMA distance pass, double-buffered with prefetch + XOR-swizzled LDS.
// dot = sum_{k<384} with A=[hi|hi|lo], B=[hi|lo|hi] from XS=[hi|lo].
// LDS layout: A0@0, A1@16K, B0@32K, B1@48K (each [128 rows][64 shorts],
// byte col ^= ((row&7)<<4) — applied on the global SOURCE address for
// global_load_lds (linear dest) and on the ds_read side).
template <int PASS>
__global__ __launch_bounds__(256, 2)
void pass_kernel(const unsigned short* __restrict__ XS, const int* __restrict__ y,
                 const float* __restrict__ sq, const float* __restrict__ anchor,
                 float* __restrict__ top4p, int* __restrict__ cntp) {
    __shared__ __align__(16) char smem[65536];

    const int t = threadIdx.x;
    const int w = t >> 6, l = t & 63;
    const int wr = w >> 1, wc = w & 1;
    const int lg = l >> 4, lo16 = l & 15;

    // XCD-aware bijective swizzle (2048 % 8 == 0)
    int bid = blockIdx.x;
    int wg = (bid & 7) * ((ITILES * NJG) >> 3) + (bid >> 3);
    const int it = wg & (ITILES - 1), jg = wg / ITILES;
    const int ibase = it * BM;

    float sqi[16]; int yi[16]; float anc[16];
    #pragma unroll
    for (int mi = 0; mi < 4; ++mi)
        #pragma unroll
        for (int r = 0; r < 4; ++r) {
            int row = ibase + wr * 64 + mi * 16 + lg * 4 + r;
            sqi[mi * 4 + r] = sq[row];
            if (PASS == 1) yi[mi * 4 + r] = y[row];
            else anc[mi * 4 + r] = anchor[row];
        }

    // staging source addressing (pre-swizzled column)
    const int srow = w * 32 + (l >> 3);
    const int scol = (((l & 7) ^ (l >> 3)) << 3);  // shorts
    const int swz = (lo16 & 7) << 4;               // read-side byte XOR

    auto STAGE = [&](int s) {
        const int ks = s % 6;
        const int jbase = jg * (BN * NJT) + (s / 6) * BN;
        const int kA = (ks < 4) ? (ks & 1) * 64 : (ks - 2) * 64;
        const int kB = (ks < 4) ? ks * 64 : (ks - 4) * 64;
        char* Ab = smem + (s & 1) * 16384 + w * 4096;
        char* Bb = smem + 32768 + (s & 1) * 16384 + w * 4096;
        const bool doA = (ks < 2) || (ks >= 4);  // ks 2,3 reuse A-hi already resident
        if (doA) {
            #pragma unroll
            for (int q = 0; q < 4; ++q)
                gload_lds16(XS + (size_t)(ibase + srow + q * 8) * 256 + kA + scol, Ab + q * 1024);
        }
        #pragma unroll
        for (int q = 0; q < 4; ++q)
            gload_lds16(XS + (size_t)(jbase + srow + q * 8) * 256 + kB + scol, Bb + q * 1024);
    };

    f32x4 acc[4][4];
    float sqj[4]; int yj[4];
    float rr0 = 1e30f, rr1 = 1e30f, rr2 = 1e30f, rr3 = 1e30f;
    int cnt16[16];
    if (PASS == 2) {
        #pragma unroll
        for (int c = 0; c < 16; ++c) cnt16[c] = 0;
    }

    STAGE(0);
    __syncthreads();

    #pragma unroll
    for (int s = 0; s < NSTEP; ++s) {
        const int ks = s % 6;
        if (ks == 0) {
            const int jbase = jg * (BN * NJT) + (s / 6) * BN;
            f32x4 zz = {0.0f, 0.0f, 0.0f, 0.0f};
            #pragma unroll
            for (int mi = 0; mi < 4; ++mi)
                #pragma unroll
                for (int ni = 0; ni < 4; ++ni) acc[mi][ni] = zz;
            #pragma unroll
            for (int ni = 0; ni < 4; ++ni) {
                int col = jbase + wc * 64 + ni * 16 + lo16;
                sqj[ni] = sq[col];
                if (PASS == 1) yj[ni] = y[col];
            }
        }
        if (s < NSTEP - 1) STAGE(s + 1);   // prefetch flies under this step's MFMAs
        {
            const char* Asc = smem + (s & 1) * 16384;
            const char* Bsc = smem + 32768 + (s & 1) * 16384;
            #pragma unroll
            for (int kk = 0; kk < 2; ++kk) {
                const int cA = (kk * 64 + lg * 16) ^ swz;
                short8 aF[4], bF[4];
                #pragma unroll
                for (int mi = 0; mi < 4; ++mi)
                    aF[mi] = *(const short8*)(Asc + (wr * 64 + mi * 16 + lo16) * 128 + cA);
                #pragma unroll
                for (int ni = 0; ni < 4; ++ni)
                    bF[ni] = *(const short8*)(Bsc + (wc * 64 + ni * 16 + lo16) * 128 + cA);
                #pragma unroll
                for (int mi = 0; mi < 4; ++mi)
                    #pragma unroll
                    for (int ni = 0; ni < 4; ++ni)
                        acc[mi][ni] = __builtin_amdgcn_mfma_f32_16x16x32_bf16(
                            aF[mi], bF[ni], acc[mi][ni], 0, 0, 0);
            }
        }
        if (ks == 5) {
            if (PASS == 1) {
                __syncthreads();                    // all waves done reading A1/B1
                float* scr = (float*)(smem + 16384);  // alias A1: [128][32] floats
                #pragma unroll
                for (int mi = 0; mi < 4; ++mi)
                    #pragma unroll
                    for (int r = 0; r < 4; ++r) {
                        float v0 = 1e30f, v1 = 1e30f, v2 = 1e30f, v3 = 1e30f;
                        #pragma unroll
                        for (int ni = 0; ni < 4; ++ni) {
                            float d2 = fmaf(-2.0f, acc[mi][ni][r], sqi[mi * 4 + r] + sqj[ni]);
                            d2 = fmaxf(d2, 0.0f);
                            float v = (yi[mi * 4 + r] == yj[ni]) ? d2 : 1e30f;
                            ins4(v, v0, v1, v2, v3);
                        }
                        #pragma unroll
                        for (int mk = 1; mk <= 2; mk <<= 1) {
                            float u0 = __shfl_xor(v0, mk), u1 = __shfl_xor(v1, mk);
                            float u2 = __shfl_xor(v2, mk), u3 = __shfl_xor(v3, mk);
                            float m0 = fminf(v0, u3), m1 = fminf(v1, u2);
                            float m2 = fminf(v2, u1), m3 = fminf(v3, u0);
                            cmpswap(m0, m2); cmpswap(m1, m3);
                            cmpswap(m0, m1); cmpswap(m2, m3);
                            v0 = m0; v1 = m1; v2 = m2; v3 = m3;
                        }
                        if ((l & 3) == 0) {
                            float4 st; st.x = v0; st.y = v1; st.z = v2; st.w = v3;
                            *(float4*)(scr + (wr * 64 + mi * 16 + lg * 4 + r) * 32 + wc * 16 + lo16) = st;
                        }
                    }
                __syncthreads();
                if (t < 128) {
                    #pragma unroll 8
                    for (int c = 0; c < 32; ++c) {
                        float v = scr[t * 32 + (c ^ (t & 31))];
                        ins4(v, rr0, rr1, rr2, rr3);
                    }
                }
            } else {
                #pragma unroll
                for (int mi = 0; mi < 4; ++mi)
                    #pragma unroll
                    for (int r = 0; r < 4; ++r) {
                        int c = 0;
                        #pragma unroll
                        for (int ni = 0; ni < 4; ++ni) {
                            float d2 = fmaf(-2.0f, acc[mi][ni][r], sqi[mi * 4 + r] + sqj[ni]);
                            d2 = fmaxf(d2, 0.0f);
                            c += (d2 <= anc[mi * 4 + r]) ? 1 : 0;
                        }
                        cnt16[mi * 4 + r] += c;
                    }
            }
        }
        __syncthreads();
    }

    if (PASS == 1) {
        if (t < 128) {
            size_t b = ((size_t)(ibase + t) * NJG + jg) * 4;
            top4p[b + 0] = rr0; top4p[b + 1] = rr1;
            top4p[b + 2] = rr2; top4p[b + 3] = rr3;
        }
    } else {
        int* scri = (int*)(smem + 16384);  // [128][2] ints (A1 free after last barrier)
        #pragma unroll
        for (int mi = 0; mi < 4; ++mi)
            #pragma unroll
            for (int r = 0; r < 4; ++r) {
                int c = cnt16[mi * 4 + r];
                c += __shfl_xor(c, 1); c += __shfl_xor(c, 2);
                c += __shfl_xor(c, 4); c += __shfl_xor(c, 8);
                if (lo16 == 0) scri[(wr * 64 + mi * 16 + lg * 4 + r) * 2 + wc] = c;
            }
        __syncthreads();
        if (t < 128) cntp[(size_t)(ibase + t) * NJG + jg] = scri[t * 2] + scri[t * 2 + 1];
    }
}

__global__ void anchor_kernel(const float* __restrict__ top4p, float* __restrict__ anchor) {
    int row = blockIdx.x * 256 + threadIdx.x;
    if (row >= NTOT) return;
    float b0 = 1e30f, b1 = 1e30f, b2 = 1e30f, b3 = 1e30f;
    const float* p = top4p + (size_t)row * NJG * 4;
    for (int c = 0; c < NJG * 4; ++c) ins4(p[c], b0, b1, b2, b3);
    anchor[row] = b3;
}

__global__ void reduce_kernel(const int* __restrict__ cntp, float* __restrict__ partials) {
    __shared__ float red[256];
    int t = threadIdx.x;
    int row = blockIdx.x * 256 + t;
    int s = 0;
    for (int c = 0; c < NJG; ++c) s += cntp[(size_t)row * NJG + c];
    red[t] = digammaf_dev((float)(s - 1));
    __syncthreads();
    for (int h = 128; h > 0; h >>= 1) {
        if (t < h) red[t] += red[t + h];
        __syncthreads();
    }
    if (t == 0) partials[blockIdx.x] = red[0];
}

__global__ void finalize_kernel(const float* __restrict__ partials, const int* __restrict__ cls,
                                float* __restrict__ out) {
    if (threadIdx.x == 0) {
        float acc = 0.0f;
        for (int c = 0; c < NTOT / 256; ++c) acc += partials[c];
        float Nf = (float)NTOT;
        float avg_m = acc / Nf;
        float avgNx = 0.0f;
        for (int c = 0; c < NCLS; ++c) {
            float nx = (float)cls[c];
            if (nx > 0.0f) avgNx += (nx / Nf) * digammaf_dev(nx);
        }
        float mi = digammaf_dev(Nf) - avgNx + digammaf_dev(3.0f) - avg_m;
        out[0] = fmaxf(mi / logf(2.0f), 0.0f);
    }
}

extern "C" void kernel_launch(void* const* d_in, const int* in_sizes, int n_in,
                              void* d_out, int out_size, void* d_ws, size_t ws_size,
                              hipStream_t stream) {
    const float* X = (const float*)d_in[0];
    const int* y = (const int*)d_in[1];
    float* out = (float*)d_out;

    float* sq       = (float*)d_ws;                                   // 8192
    float* anchors  = sq + NTOT;                                      // 8192
    float* partials = anchors + NTOT;                                 // 64
    int*   cls      = (int*)(partials + 64);                          // 16
    unsigned short* XS = (unsigned short*)(cls + 16);                 // 8192*256 (16B-aligned)
    float* top4p    = (float*)(XS + (size_t)NTOT * 256);              // 8192*32*4
    int*   cntp     = (int*)(top4p + (size_t)NTOT * NJG * 4);         // 8192*32

    zero_kernel<<<1, 64, 0, stream>>>(cls);
    prep_kernel<<<NTOT / 4, 256, 0, stream>>>(X, y, sq, XS, cls);
    pass_kernel<1><<<ITILES * NJG, 256, 0, stream>>>(XS, y, sq, anchors, top4p, cntp);
    anchor_kernel<<<NTOT / 256, 256, 0, stream>>>(top4p, anchors);
    pass_kernel<2><<<ITILES * NJG, 256, 0, stream>>>(XS, y, sq, anchors, top4p, cntp);
    reduce_kernel<<<NTOT / 256, 256, 0, stream>>>(cntp, partials);
    finalize_kernel<<<1, 64, 0, stream>>>(partials, cls, out);
}

// Round 4
// 261.083 us; speedup vs baseline: 2.8466x; 1.2265x over previous
//
#include <hip/hip_runtime.h>
#include <hip/hip_bf16.h>
#include <math.h>

#define NCLS 10
#define NTOT 8192
#define BM 128
#define BN 128
#define NJT 8
#define NJG (NTOT / (BN * NJT))   // 8
#define ITILES (NTOT / BM)        // 64

using short8 = __attribute__((ext_vector_type(8))) short;
using f32x4  = __attribute__((ext_vector_type(4))) float;

__device__ __forceinline__ float digammaf_dev(float x) {
    float r = 0.0f;
    while (x < 6.0f) { r -= 1.0f / x; x += 1.0f; }
    float inv = 1.0f / x;
    float inv2 = inv * inv;
    float s = logf(x) - 0.5f * inv
            - inv2 * (0.083333333333f - inv2 * (0.0083333333333f - inv2 * 0.0039682539683f));
    return r + s;
}

__device__ __forceinline__ void cmpswap(float& a, float& b) {
    float lo = fminf(a, b), hi = fmaxf(a, b);
    a = lo; b = hi;
}

// branchless insert of v into ascending quad, keep 4 smallest (7 ops)
__device__ __forceinline__ void ins7(float v, float& b0, float& b1, float& b2, float& b3) {
    float x0 = fminf(b0, v); float c0 = fmaxf(b0, v);
    float x1 = fminf(b1, c0); float c1 = fmaxf(b1, c0);
    float x2 = fminf(b2, c1); float c2 = fmaxf(b2, c1);
    float x3 = fminf(b3, c2);
    b0 = x0; b1 = x1; b2 = x2; b3 = x3;
}

__device__ __forceinline__ void gload_lds16(const void* g, void* s) {
    __builtin_amdgcn_global_load_lds((const __attribute__((address_space(1))) void*)g,
                                     (__attribute__((address_space(3))) void*)s, 16, 0, 0);
}

__global__ void zero_kernel(int* cls) {
    if (threadIdx.x < 16) cls[threadIdx.x] = 0;
}

// per row: sq (fp32), class bincount, XS[row][0..127]=hi(bf16), [128..255]=lo(bf16)
__global__ void prep_kernel(const float* __restrict__ X, const int* __restrict__ y,
                            float* __restrict__ sq, unsigned short* __restrict__ XS,
                            int* __restrict__ cls) {
    int wave = threadIdx.x >> 6, lane = threadIdx.x & 63;
    int row = blockIdx.x * 4 + wave;
    float2 v = *(const float2*)(X + (size_t)row * 128 + lane * 2);
    __hip_bfloat16 h0 = __float2bfloat16(v.x);
    __hip_bfloat16 h1 = __float2bfloat16(v.y);
    float hf0 = __bfloat162float(h0), hf1 = __bfloat162float(h1);
    __hip_bfloat16 l0 = __float2bfloat16(v.x - hf0);
    __hip_bfloat16 l1 = __float2bfloat16(v.y - hf1);
    ushort2 hp, lp;
    hp.x = *(unsigned short*)&h0; hp.y = *(unsigned short*)&h1;
    lp.x = *(unsigned short*)&l0; lp.y = *(unsigned short*)&l1;
    *(ushort2*)(XS + (size_t)row * 256 + lane * 2) = hp;
    *(ushort2*)(XS + (size_t)row * 256 + 128 + lane * 2) = lp;
    float s = fmaf(v.x, v.x, v.y * v.y);
    #pragma unroll
    for (int off = 32; off > 0; off >>= 1) s += __shfl_down(s, off);
    if (lane == 0) {
        sq[row] = s;
        atomicAdd(&cls[y[row]], 1);
    }
}

// MFMA distance pass; double-buffered, XOR-swizzled LDS, precomputed addresses,
// register-resident running top-4 (pass 1) / counts (pass 2).
template <int PASS>
__global__ __launch_bounds__(256, 2)
void pass_kernel(const unsigned short* __restrict__ XS, const int* __restrict__ y,
                 const float* __restrict__ sq, const float* __restrict__ anchor,
                 float* __restrict__ top4p, int* __restrict__ cntp) {
    __shared__ __align__(16) char smem[65536];

    const int t = threadIdx.x;
    const int w = t >> 6, l = t & 63;
    const int wr = w >> 1, wc = w & 1;
    const int lg = l >> 4, lo16 = l & 15;

    // XCD-aware bijective swizzle (512 % 8 == 0)
    const int bid = blockIdx.x;
    const int wg = (bid & 7) * ((ITILES * NJG) >> 3) + (bid >> 3);
    const int it = wg % ITILES, jg = wg / ITILES;
    const int ibase = it * BM;
    const int jg0 = jg * (BN * NJT);

    float sqi[16]; int yi[16]; float anc[16];
    #pragma unroll
    for (int mi = 0; mi < 4; ++mi)
        #pragma unroll
        for (int r = 0; r < 4; ++r) {
            int row = ibase + wr * 64 + mi * 16 + lg * 4 + r;
            sqi[mi * 4 + r] = sq[row];
            if (PASS == 1) yi[mi * 4 + r] = y[row];
            else anc[mi * 4 + r] = anchor[row];
        }

    // precomputed LDS read byte-offsets (vaddr); parity/mi/ni folded as immediates
    const int swz = (lo16 & 7) << 4;
    unsigned aoff[2], boff[2];
    #pragma unroll
    for (int kk = 0; kk < 2; ++kk) {
        const int cA = (kk * 64 + lg * 16) ^ swz;
        aoff[kk] = (unsigned)((wr * 64 + lo16) * 128 + cA);
        boff[kk] = (unsigned)(32768 + (wc * 64 + lo16) * 128 + cA);
    }
    // staging: per-lane source base + wave-uniform step offsets
    const int srow = w * 32 + (l >> 3);
    const int scol = ((l & 7) ^ (l >> 3)) << 3;           // pre-swizzled shorts
    const unsigned short* gsrc = XS + (size_t)srow * 256 + scol;

    auto STAGE = [&](int jbase_rows, int ks, int par) {
        if (ks < 2 || ks >= 4) {                          // ks 2,3 reuse resident A-hi
            const int kA = (ks < 4) ? (ks & 1) * 64 : (ks - 2) * 64;
            char* Ab = smem + par * 16384 + w * 4096;
            const unsigned short* gA = gsrc + (size_t)ibase * 256 + kA;
            #pragma unroll
            for (int q = 0; q < 4; ++q)
                gload_lds16(gA + (size_t)q * 8 * 256, Ab + q * 1024);
        }
        const int kB = (ks < 4) ? ks * 64 : (ks - 4) * 64;
        char* Bb = smem + 32768 + par * 16384 + w * 4096;
        const unsigned short* gB = gsrc + (size_t)jbase_rows * 256 + kB;
        #pragma unroll
        for (int q = 0; q < 4; ++q)
            gload_lds16(gB + (size_t)q * 8 * 256, Bb + q * 1024);
    };

    float tp0[16], tp1[16], tp2[16], tp3[16];
    int cnt16[16];
    #pragma unroll
    for (int c = 0; c < 16; ++c) {
        if (PASS == 1) { tp0[c] = 1e30f; tp1[c] = 1e30f; tp2[c] = 1e30f; tp3[c] = 1e30f; }
        else cnt16[c] = 0;
    }

    STAGE(jg0, 0, 0);
    __syncthreads();

    #pragma unroll 1
    for (int jt = 0; jt < NJT; ++jt) {
        const int jbase = jg0 + jt * BN;
        float sqj[4]; int yj[4];
        #pragma unroll
        for (int ni = 0; ni < 4; ++ni) {
            int col = jbase + wc * 64 + ni * 16 + lo16;
            sqj[ni] = sq[col];
            if (PASS == 1) yj[ni] = y[col];
        }
        f32x4 acc[4][4];
        f32x4 zz = {0.0f, 0.0f, 0.0f, 0.0f};
        #pragma unroll
        for (int mi = 0; mi < 4; ++mi)
            #pragma unroll
            for (int ni = 0; ni < 4; ++ni) acc[mi][ni] = zz;

        #pragma unroll
        for (int ks = 0; ks < 6; ++ks) {
            const int par = ks & 1;
            if (ks < 5) STAGE(jbase, ks + 1, par ^ 1);
            else if (jt < NJT - 1) STAGE(jbase + BN, 0, par ^ 1);

            #pragma unroll
            for (int kk = 0; kk < 2; ++kk) {
                short8 aF[4], bF[4];
                #pragma unroll
                for (int mi = 0; mi < 4; ++mi)
                    aF[mi] = *(const short8*)(smem + aoff[kk] + par * 16384 + mi * 2048);
                #pragma unroll
                for (int ni = 0; ni < 4; ++ni)
                    bF[ni] = *(const short8*)(smem + boff[kk] + par * 16384 + ni * 2048);
                #pragma unroll
                for (int mi = 0; mi < 4; ++mi)
                    #pragma unroll
                    for (int ni = 0; ni < 4; ++ni)
                        acc[mi][ni] = __builtin_amdgcn_mfma_f32_16x16x32_bf16(
                            aF[mi], bF[ni], acc[mi][ni], 0, 0, 0);
            }

            if (ks == 5) {  // full K=384 accumulated: fold this jt into running state
                if (PASS == 1) {
                    #pragma unroll
                    for (int mi = 0; mi < 4; ++mi)
                        #pragma unroll
                        for (int r = 0; r < 4; ++r) {
                            const int idx = mi * 4 + r;
                            #pragma unroll
                            for (int ni = 0; ni < 4; ++ni) {
                                float d2 = fmaf(-2.0f, acc[mi][ni][r], sqi[idx] + sqj[ni]);
                                d2 = fmaxf(d2, 0.0f);
                                float v = (yi[idx] == yj[ni]) ? d2 : 1e30f;
                                ins7(v, tp0[idx], tp1[idx], tp2[idx], tp3[idx]);
                            }
                        }
                } else {
                    #pragma unroll
                    for (int mi = 0; mi < 4; ++mi)
                        #pragma unroll
                        for (int r = 0; r < 4; ++r) {
                            const int idx = mi * 4 + r;
                            int c = 0;
                            #pragma unroll
                            for (int ni = 0; ni < 4; ++ni) {
                                float d2 = fmaf(-2.0f, acc[mi][ni][r], sqi[idx] + sqj[ni]);
                                d2 = fmaxf(d2, 0.0f);
                                c += (d2 <= anc[idx]) ? 1 : 0;
                            }
                            cnt16[idx] += c;
                        }
                }
            }
            __syncthreads();
        }
    }

    // one-shot cross-lane + cross-wave merge
    if (PASS == 1) {
        float* scr = (float*)smem;  // [128 rows][2 wc][4]
        #pragma unroll
        for (int idx = 0; idx < 16; ++idx) {
            float v0 = tp0[idx], v1 = tp1[idx], v2 = tp2[idx], v3 = tp3[idx];
            #pragma unroll
            for (int mk = 1; mk <= 8; mk <<= 1) {
                float u0 = __shfl_xor(v0, mk), u1 = __shfl_xor(v1, mk);
                float u2 = __shfl_xor(v2, mk), u3 = __shfl_xor(v3, mk);
                float m0 = fminf(v0, u3), m1 = fminf(v1, u2);
                float m2 = fminf(v2, u1), m3 = fminf(v3, u0);
                cmpswap(m0, m2); cmpswap(m1, m3);
                cmpswap(m0, m1); cmpswap(m2, m3);
                v0 = m0; v1 = m1; v2 = m2; v3 = m3;
            }
            if (lo16 == 0) {
                int rl = wr * 64 + (idx >> 2) * 16 + lg * 4 + (idx & 3);
                float4 st; st.x = v0; st.y = v1; st.z = v2; st.w = v3;
                *(float4*)(scr + rl * 8 + wc * 4) = st;
            }
        }
        __syncthreads();
        if (t < 128) {
            float4 qa = *(float4*)(scr + t * 8);
            float4 qb = *(float4*)(scr + t * 8 + 4);
            float b0 = qa.x, b1 = qa.y, b2 = qa.z, b3 = qa.w;
            ins7(qb.x, b0, b1, b2, b3); ins7(qb.y, b0, b1, b2, b3);
            ins7(qb.z, b0, b1, b2, b3); ins7(qb.w, b0, b1, b2, b3);
            size_t base = ((size_t)(ibase + t) * NJG + jg) * 4;
            top4p[base + 0] = b0; top4p[base + 1] = b1;
            top4p[base + 2] = b2; top4p[base + 3] = b3;
        }
    } else {
        int* scri = (int*)smem;  // [128][2]
        #pragma unroll
        for (int idx = 0; idx < 16; ++idx) {
            int c = cnt16[idx];
            c += __shfl_xor(c, 1); c += __shfl_xor(c, 2);
            c += __shfl_xor(c, 4); c += __shfl_xor(c, 8);
            if (lo16 == 0) {
                int rl = wr * 64 + (idx >> 2) * 16 + lg * 4 + (idx & 3);
                scri[rl * 2 + wc] = c;
            }
        }
        __syncthreads();
        if (t < 128) cntp[(size_t)(ibase + t) * NJG + jg] = scri[t * 2] + scri[t * 2 + 1];
    }
}

__global__ void anchor_kernel(const float* __restrict__ top4p, float* __restrict__ anchor) {
    int row = blockIdx.x * 256 + threadIdx.x;
    if (row >= NTOT) return;
    float b0 = 1e30f, b1 = 1e30f, b2 = 1e30f, b3 = 1e30f;
    const float* p = top4p + (size_t)row * NJG * 4;
    for (int c = 0; c < NJG * 4; ++c) ins7(p[c], b0, b1, b2, b3);
    anchor[row] = b3;
}

__global__ void reduce_kernel(const int* __restrict__ cntp, float* __restrict__ partials) {
    __shared__ float red[256];
    int t = threadIdx.x;
    int row = blockIdx.x * 256 + t;
    int s = 0;
    for (int c = 0; c < NJG; ++c) s += cntp[(size_t)row * NJG + c];
    red[t] = digammaf_dev((float)(s - 1));
    __syncthreads();
    for (int h = 128; h > 0; h >>= 1) {
        if (t < h) red[t] += red[t + h];
        __syncthreads();
    }
    if (t == 0) partials[blockIdx.x] = red[0];
}

__global__ void finalize_kernel(const float* __restrict__ partials, const int* __restrict__ cls,
                                float* __restrict__ out) {
    if (threadIdx.x == 0) {
        float acc = 0.0f;
        for (int c = 0; c < NTOT / 256; ++c) acc += partials[c];
        float Nf = (float)NTOT;
        float avg_m = acc / Nf;
        float avgNx = 0.0f;
        for (int c = 0; c < NCLS; ++c) {
            float nx = (float)cls[c];
            if (nx > 0.0f) avgNx += (nx / Nf) * digammaf_dev(nx);
        }
        float mi = digammaf_dev(Nf) - avgNx + digammaf_dev(3.0f) - avg_m;
        out[0] = fmaxf(mi / logf(2.0f), 0.0f);
    }
}

extern "C" void kernel_launch(void* const* d_in, const int* in_sizes, int n_in,
                              void* d_out, int out_size, void* d_ws, size_t ws_size,
                              hipStream_t stream) {
    const float* X = (const float*)d_in[0];
    const int* y = (const int*)d_in[1];
    float* out = (float*)d_out;

    float* sq       = (float*)d_ws;                                   // 8192
    float* anchors  = sq + NTOT;                                      // 8192
    float* partials = anchors + NTOT;                                 // 64
    int*   cls      = (int*)(partials + 64);                          // 16
    unsigned short* XS = (unsigned short*)(cls + 16);                 // 8192*256 (16B-aligned)
    float* top4p    = (float*)(XS + (size_t)NTOT * 256);              // 8192*8*4
    int*   cntp     = (int*)(top4p + (size_t)NTOT * NJG * 4);         // 8192*8

    zero_kernel<<<1, 64, 0, stream>>>(cls);
    prep_kernel<<<NTOT / 4, 256, 0, stream>>>(X, y, sq, XS, cls);
    pass_kernel<1><<<ITILES * NJG, 256, 0, stream>>>(XS, y, sq, anchors, top4p, cntp);
    anchor_kernel<<<NTOT / 256, 256, 0, stream>>>(top4p, anchors);
    pass_kernel<2><<<ITILES * NJG, 256, 0, stream>>>(XS, y, sq, anchors, top4p, cntp);
    reduce_kernel<<<NTOT / 256, 256, 0, stream>>>(cntp, partials);
    finalize_kernel<<<1, 64, 0, stream>>>(partials, cls, out);
}

// Round 5
// 159.869 us; speedup vs baseline: 4.6489x; 1.6331x over previous
//
#include <hip/hip_runtime.h>
#include <hip/hip_bf16.h>
#include <math.h>

#define NCLS 10
#define NTOT 8192
#define NTIL 64                  // 8192/128 tiles per side
#define NBLK (NTIL * (NTIL + 1) / 2)   // 2080 upper-triangle tiles

using short8 = __attribute__((ext_vector_type(8))) short;
using f32x4  = __attribute__((ext_vector_type(4))) float;

__device__ __forceinline__ float digammaf_dev(float x) {
    float r = 0.0f;
    while (x < 6.0f) { r -= 1.0f / x; x += 1.0f; }
    float inv = 1.0f / x;
    float inv2 = inv * inv;
    float s = logf(x) - 0.5f * inv
            - inv2 * (0.083333333333f - inv2 * (0.0083333333333f - inv2 * 0.0039682539683f));
    return r + s;
}

__device__ __forceinline__ void cmpswap(float& a, float& b) {
    float lo = fminf(a, b), hi = fmaxf(a, b);
    a = lo; b = hi;
}

// branchless insert of v into ascending quad, keep 4 smallest
__device__ __forceinline__ void ins7(float v, float& b0, float& b1, float& b2, float& b3) {
    float x0 = fminf(b0, v); float c0 = fmaxf(b0, v);
    float x1 = fminf(b1, c0); float c1 = fmaxf(b1, c0);
    float x2 = fminf(b2, c1); float c2 = fmaxf(b2, c1);
    float x3 = fminf(b3, c2);
    b0 = x0; b1 = x1; b2 = x2; b3 = x3;
}

// merge my sorted quad with lane^mk's sorted quad -> 4 smallest of union, sorted
__device__ __forceinline__ void bmerge(int mk, float& v0, float& v1, float& v2, float& v3) {
    float u0 = __shfl_xor(v0, mk), u1 = __shfl_xor(v1, mk);
    float u2 = __shfl_xor(v2, mk), u3 = __shfl_xor(v3, mk);
    float m0 = fminf(v0, u3), m1 = fminf(v1, u2);
    float m2 = fminf(v2, u1), m3 = fminf(v3, u0);
    cmpswap(m0, m2); cmpswap(m1, m3);
    cmpswap(m0, m1); cmpswap(m2, m3);
    v0 = m0; v1 = m1; v2 = m2; v3 = m3;
}

__device__ __forceinline__ void gload_lds16(const void* g, void* s) {
    __builtin_amdgcn_global_load_lds((const __attribute__((address_space(1))) void*)g,
                                     (__attribute__((address_space(3))) void*)s, 16, 0, 0);
}

__global__ void zero_kernel(int* cls) {
    if (threadIdx.x < 16) cls[threadIdx.x] = 0;
}

// per row: sq (fp32), XS[row][0..127]=hi(bf16), [128..255]=lo(bf16). No atomics.
__global__ void prep_kernel(const float* __restrict__ X,
                            float* __restrict__ sq, unsigned short* __restrict__ XS) {
    int wave = threadIdx.x >> 6, lane = threadIdx.x & 63;
    int row = blockIdx.x * 4 + wave;
    float2 v = *(const float2*)(X + (size_t)row * 128 + lane * 2);
    __hip_bfloat16 h0 = __float2bfloat16(v.x);
    __hip_bfloat16 h1 = __float2bfloat16(v.y);
    float hf0 = __bfloat162float(h0), hf1 = __bfloat162float(h1);
    __hip_bfloat16 l0 = __float2bfloat16(v.x - hf0);
    __hip_bfloat16 l1 = __float2bfloat16(v.y - hf1);
    ushort2 hp, lp;
    hp.x = *(unsigned short*)&h0; hp.y = *(unsigned short*)&h1;
    lp.x = *(unsigned short*)&l0; lp.y = *(unsigned short*)&l1;
    *(ushort2*)(XS + (size_t)row * 256 + lane * 2) = hp;
    *(ushort2*)(XS + (size_t)row * 256 + 128 + lane * 2) = lp;
    float s = fmaf(v.x, v.x, v.y * v.y);
    #pragma unroll
    for (int off = 32; off > 0; off >>= 1) s += __shfl_down(s, off);
    if (lane == 0) sq[row] = s;
}

// Triangular MFMA distance pass: one 128x128 tile (it<=jt) per block.
// Row-side results -> slot (i, jt); col-side (non-diag) -> slot (j, it).
template <int PASS>
__global__ __launch_bounds__(256, 2)
void pass_kernel(const unsigned short* __restrict__ XS, const int* __restrict__ y,
                 const float* __restrict__ sq, const float* __restrict__ anchor,
                 float* __restrict__ top4p, int* __restrict__ cntp) {
    __shared__ __align__(16) char smem[65536];

    const int t = threadIdx.x;
    const int w = t >> 6, l = t & 63;
    const int wr = w >> 1, wc = w & 1;
    const int lg = l >> 4, lo16 = l & 15;

    // XCD-aware swizzle (2080 = 8*260), then triangle decode
    const int bid = blockIdx.x;
    const int wg = (bid & 7) * (NBLK / 8) + (bid >> 3);
    int it = (int)((129.0f - sqrtf(fmaf(-8.0f, (float)wg, 16641.0f))) * 0.5f);
    while ((it + 1) * NTIL - ((it + 1) * it) / 2 <= wg) ++it;
    while (it * NTIL - (it * (it - 1)) / 2 > wg) --it;
    const int jt = it + (wg - (it * NTIL - (it * (it - 1)) / 2));
    const int ibase = it * 128, jbase = jt * 128;
    const bool diag = (it == jt);

    float sqi[16]; int yi[16]; float anc_i[16];
    #pragma unroll
    for (int mi = 0; mi < 4; ++mi)
        #pragma unroll
        for (int r = 0; r < 4; ++r) {
            int row = ibase + wr * 64 + mi * 16 + lg * 4 + r;
            sqi[mi * 4 + r] = sq[row];
            if (PASS == 1) yi[mi * 4 + r] = y[row];
            else anc_i[mi * 4 + r] = anchor[row];
        }
    float sqj[4]; int yj[4]; float anc_j[4];
    #pragma unroll
    for (int ni = 0; ni < 4; ++ni) {
        int col = jbase + wc * 64 + ni * 16 + lo16;
        sqj[ni] = sq[col];
        if (PASS == 1) yj[ni] = y[col];
        else anc_j[ni] = anchor[col];
    }

    // precomputed LDS read byte-offsets
    const int swz = (lo16 & 7) << 4;
    unsigned aoff[2], boff[2];
    #pragma unroll
    for (int kk = 0; kk < 2; ++kk) {
        const int cA = (kk * 64 + lg * 16) ^ swz;
        aoff[kk] = (unsigned)((wr * 64 + lo16) * 128 + cA);
        boff[kk] = (unsigned)(32768 + (wc * 64 + lo16) * 128 + cA);
    }
    // staging: per-lane source base + uniform offsets (pre-swizzled column)
    const int srow = w * 32 + (l >> 3);
    const int scol = ((l & 7) ^ (l >> 3)) << 3;
    const unsigned short* gsrc = XS + (size_t)srow * 256 + scol;

    auto STAGE = [&](int ks, int par) {
        if (ks < 2 || ks >= 4) {                        // ks 2,3 reuse resident A-hi
            const int kA = (ks < 4) ? (ks & 1) * 64 : (ks - 2) * 64;
            char* Ab = smem + par * 16384 + w * 4096;
            const unsigned short* gA = gsrc + (size_t)ibase * 256 + kA;
            #pragma unroll
            for (int q = 0; q < 4; ++q)
                gload_lds16(gA + (size_t)q * 8 * 256, Ab + q * 1024);
        }
        const int kB = (ks < 4) ? ks * 64 : (ks - 4) * 64;
        char* Bb = smem + 32768 + par * 16384 + w * 4096;
        const unsigned short* gB = gsrc + (size_t)jbase * 256 + kB;
        #pragma unroll
        for (int q = 0; q < 4; ++q)
            gload_lds16(gB + (size_t)q * 8 * 256, Bb + q * 1024);
    };

    f32x4 acc[4][4];
    f32x4 zz = {0.0f, 0.0f, 0.0f, 0.0f};
    #pragma unroll
    for (int mi = 0; mi < 4; ++mi)
        #pragma unroll
        for (int ni = 0; ni < 4; ++ni) acc[mi][ni] = zz;

    STAGE(0, 0);
    __syncthreads();

    #pragma unroll
    for (int ks = 0; ks < 6; ++ks) {
        const int par = ks & 1;
        if (ks < 5) STAGE(ks + 1, par ^ 1);
        #pragma unroll
        for (int kk = 0; kk < 2; ++kk) {
            short8 aF[4], bF[4];
            #pragma unroll
            for (int mi = 0; mi < 4; ++mi)
                aF[mi] = *(const short8*)(smem + aoff[kk] + par * 16384 + mi * 2048);
            #pragma unroll
            for (int ni = 0; ni < 4; ++ni)
                bF[ni] = *(const short8*)(smem + boff[kk] + par * 16384 + ni * 2048);
            #pragma unroll
            for (int mi = 0; mi < 4; ++mi)
                #pragma unroll
                for (int ni = 0; ni < 4; ++ni)
                    acc[mi][ni] = __builtin_amdgcn_mfma_f32_16x16x32_bf16(
                        aF[mi], bF[ni], acc[mi][ni], 0, 0, 0);
        }
        __syncthreads();
    }

    if (PASS == 1) {
        float* scrR = (float*)smem;            // [128][8]
        float* scrC = (float*)(smem + 4096);   // [128][8]
        // row-side top-4 (same-class) over this tile's 128 cols
        #pragma unroll
        for (int mi = 0; mi < 4; ++mi)
            #pragma unroll
            for (int r = 0; r < 4; ++r) {
                const int idx = mi * 4 + r;
                float v0 = 1e30f, v1 = 1e30f, v2 = 1e30f, v3 = 1e30f;
                #pragma unroll
                for (int ni = 0; ni < 4; ++ni) {
                    float d2 = fmaf(-2.0f, acc[mi][ni][r], sqi[idx] + sqj[ni]);
                    d2 = fmaxf(d2, 0.0f);
                    float v = (yi[idx] == yj[ni]) ? d2 : 1e30f;
                    ins7(v, v0, v1, v2, v3);
                }
                bmerge(1, v0, v1, v2, v3); bmerge(2, v0, v1, v2, v3);
                bmerge(4, v0, v1, v2, v3); bmerge(8, v0, v1, v2, v3);
                if (lo16 == 0) {
                    int rl = wr * 64 + mi * 16 + lg * 4 + r;
                    float4 st; st.x = v0; st.y = v1; st.z = v2; st.w = v3;
                    *(float4*)(scrR + rl * 8 + wc * 4) = st;
                }
            }
        // col-side top-4 over this tile's 128 rows (skip on diagonal)
        if (!diag) {
            #pragma unroll
            for (int ni = 0; ni < 4; ++ni) {
                float v0 = 1e30f, v1 = 1e30f, v2 = 1e30f, v3 = 1e30f;
                #pragma unroll
                for (int mi = 0; mi < 4; ++mi)
                    #pragma unroll
                    for (int r = 0; r < 4; ++r) {
                        const int idx = mi * 4 + r;
                        float d2 = fmaf(-2.0f, acc[mi][ni][r], sqi[idx] + sqj[ni]);
                        d2 = fmaxf(d2, 0.0f);
                        float v = (yi[idx] == yj[ni]) ? d2 : 1e30f;
                        ins7(v, v0, v1, v2, v3);
                    }
                bmerge(16, v0, v1, v2, v3); bmerge(32, v0, v1, v2, v3);
                if (lg == 0) {
                    int cl = wc * 64 + ni * 16 + lo16;
                    float4 st; st.x = v0; st.y = v1; st.z = v2; st.w = v3;
                    *(float4*)(scrC + cl * 8 + wr * 4) = st;
                }
            }
        }
        __syncthreads();
        if (t < 128) {
            float4 qa = *(float4*)(scrR + t * 8);
            float4 qb = *(float4*)(scrR + t * 8 + 4);
            float b0 = qa.x, b1 = qa.y, b2 = qa.z, b3 = qa.w;
            ins7(qb.x, b0, b1, b2, b3); ins7(qb.y, b0, b1, b2, b3);
            ins7(qb.z, b0, b1, b2, b3); ins7(qb.w, b0, b1, b2, b3);
            size_t base = ((size_t)(ibase + t) * NTIL + jt) * 4;
            top4p[base + 0] = b0; top4p[base + 1] = b1;
            top4p[base + 2] = b2; top4p[base + 3] = b3;
            if (!diag) {
                qa = *(float4*)(scrC + t * 8);
                qb = *(float4*)(scrC + t * 8 + 4);
                b0 = qa.x; b1 = qa.y; b2 = qa.z; b3 = qa.w;
                ins7(qb.x, b0, b1, b2, b3); ins7(qb.y, b0, b1, b2, b3);
                ins7(qb.z, b0, b1, b2, b3); ins7(qb.w, b0, b1, b2, b3);
                base = ((size_t)(jbase + t) * NTIL + it) * 4;
                top4p[base + 0] = b0; top4p[base + 1] = b1;
                top4p[base + 2] = b2; top4p[base + 3] = b3;
            }
        }
    } else {
        int* scriR = (int*)smem;          // [128][2]
        int* scriC = (int*)(smem + 1024); // [128][2]
        #pragma unroll
        for (int mi = 0; mi < 4; ++mi)
            #pragma unroll
            for (int r = 0; r < 4; ++r) {
                const int idx = mi * 4 + r;
                int c = 0;
                #pragma unroll
                for (int ni = 0; ni < 4; ++ni) {
                    float d2 = fmaf(-2.0f, acc[mi][ni][r], sqi[idx] + sqj[ni]);
                    d2 = fmaxf(d2, 0.0f);
                    c += (d2 <= anc_i[idx]) ? 1 : 0;
                }
                c += __shfl_xor(c, 1); c += __shfl_xor(c, 2);
                c += __shfl_xor(c, 4); c += __shfl_xor(c, 8);
                if (lo16 == 0) scriR[(wr * 64 + mi * 16 + lg * 4 + r) * 2 + wc] = c;
            }
        if (!diag) {
            #pragma unroll
            for (int ni = 0; ni < 4; ++ni) {
                int c = 0;
                #pragma unroll
                for (int mi = 0; mi < 4; ++mi)
                    #pragma unroll
                    for (int r = 0; r < 4; ++r) {
                        float d2 = fmaf(-2.0f, acc[mi][ni][r], sqi[mi * 4 + r] + sqj[ni]);
                        d2 = fmaxf(d2, 0.0f);
                        c += (d2 <= anc_j[ni]) ? 1 : 0;
                    }
                c += __shfl_xor(c, 16); c += __shfl_xor(c, 32);
                if (lg == 0) scriC[(wc * 64 + ni * 16 + lo16) * 2 + wr] = c;
            }
        }
        __syncthreads();
        if (t < 128) {
            cntp[(size_t)(ibase + t) * NTIL + jt] = scriR[t * 2] + scriR[t * 2 + 1];
            if (!diag)
                cntp[(size_t)(jbase + t) * NTIL + it] = scriC[t * 2] + scriC[t * 2 + 1];
        }
    }
}

__global__ void anchor_kernel(const float* __restrict__ top4p, float* __restrict__ anchor) {
    int row = blockIdx.x * 256 + threadIdx.x;
    if (row >= NTOT) return;
    float b0 = 1e30f, b1 = 1e30f, b2 = 1e30f, b3 = 1e30f;
    const float4* p = (const float4*)(top4p + (size_t)row * NTIL * 4);
    for (int c = 0; c < NTIL; ++c) {
        float4 q = p[c];
        ins7(q.x, b0, b1, b2, b3); ins7(q.y, b0, b1, b2, b3);
        ins7(q.z, b0, b1, b2, b3); ins7(q.w, b0, b1, b2, b3);
    }
    anchor[row] = b3;
}

// sum count partials -> digamma partial sums; also class histogram (320 atomics total)
__global__ void reduce_kernel(const int* __restrict__ cntp, const int* __restrict__ y,
                              float* __restrict__ partials, int* __restrict__ cls) {
    __shared__ float red[256];
    __shared__ int hist[NCLS];
    int t = threadIdx.x;
    if (t < NCLS) hist[t] = 0;
    __syncthreads();
    int row = blockIdx.x * 256 + t;
    int s = 0;
    for (int c = 0; c < NTIL; ++c) s += cntp[(size_t)row * NTIL + c];
    atomicAdd(&hist[y[row]], 1);
    red[t] = digammaf_dev((float)(s - 1));
    __syncthreads();
    for (int h = 128; h > 0; h >>= 1) {
        if (t < h) red[t] += red[t + h];
        __syncthreads();
    }
    if (t == 0) partials[blockIdx.x] = red[0];
    if (t < NCLS) atomicAdd(&cls[t], hist[t]);
}

__global__ void finalize_kernel(const float* __restrict__ partials, const int* __restrict__ cls,
                                float* __restrict__ out) {
    if (threadIdx.x == 0) {
        float acc = 0.0f;
        for (int c = 0; c < NTOT / 256; ++c) acc += partials[c];
        float Nf = (float)NTOT;
        float avg_m = acc / Nf;
        float avgNx = 0.0f;
        for (int c = 0; c < NCLS; ++c) {
            float nx = (float)cls[c];
            if (nx > 0.0f) avgNx += (nx / Nf) * digammaf_dev(nx);
        }
        float mi = digammaf_dev(Nf) - avgNx + digammaf_dev(3.0f) - avg_m;
        out[0] = fmaxf(mi / logf(2.0f), 0.0f);
    }
}

extern "C" void kernel_launch(void* const* d_in, const int* in_sizes, int n_in,
                              void* d_out, int out_size, void* d_ws, size_t ws_size,
                              hipStream_t stream) {
    const float* X = (const float*)d_in[0];
    const int* y = (const int*)d_in[1];
    float* out = (float*)d_out;

    float* sq       = (float*)d_ws;                                   // 8192
    float* anchors  = sq + NTOT;                                      // 8192
    float* partials = anchors + NTOT;                                 // 32
    int*   cls      = (int*)(partials + 32);                          // 16
    unsigned short* XS = (unsigned short*)(cls + 16);                 // 8192*256 (4 MB)
    float* top4p    = (float*)(XS + (size_t)NTOT * 256);              // 8192*64*4 (8 MB)
    int*   cntp     = (int*)(top4p + (size_t)NTOT * NTIL * 4);        // 8192*64 (2 MB)

    zero_kernel<<<1, 64, 0, stream>>>(cls);
    prep_kernel<<<NTOT / 4, 256, 0, stream>>>(X, sq, XS);
    pass_kernel<1><<<NBLK, 256, 0, stream>>>(XS, y, sq, anchors, top4p, cntp);
    anchor_kernel<<<NTOT / 256, 256, 0, stream>>>(top4p, anchors);
    pass_kernel<2><<<NBLK, 256, 0, stream>>>(XS, y, sq, anchors, top4p, cntp);
    reduce_kernel<<<NTOT / 256, 256, 0, stream>>>(cntp, y, partials, cls);
    finalize_kernel<<<1, 64, 0, stream>>>(partials, cls, out);
}